// Round 9
// baseline (524.306 us; speedup 1.0000x reference)
//
#include <hip/hip_runtime.h>
#include <stdint.h>

// Problem constants
constexpr int NBATCH = 4;
constexpr int CH     = 256;   // channels
constexpr int LEN    = 4096;  // sequence length
constexpr int LPOOL  = 1024;  // pooled length (LEN/4)
constexpr int NH     = 4;     // heads
constexpr int HD     = 64;    // head dim
constexpr int NBLK   = 512;   // mega-kernel grid. DEADLOCK-SAFETY: 32 KB LDS +
                              // launch_bounds(256,2) guarantees 2 blocks/CU
                              // co-resident (any VGPR<=256), 512 = 2*256 CUs.

typedef __attribute__((ext_vector_type(8))) short short8;     // 8 bf16 in 4 VGPRs
typedef __attribute__((ext_vector_type(4))) float float4e;    // MFMA C/D 16x16
typedef __attribute__((ext_vector_type(16))) float float16e;  // MFMA C/D 32x32
typedef __attribute__((ext_vector_type(2))) unsigned uint2v;

__device__ __forceinline__ unsigned short f2bf(float f) {
    union { unsigned int i; float f; } v; v.f = f;
    unsigned int lsb = (v.i >> 16) & 1u;
    v.i += 0x7fffu + lsb;
    return (unsigned short)(v.i >> 16);
}
// pack two floats -> two bf16 (round-half-up via +0x8000, then byte-perm)
__device__ __forceinline__ unsigned pack2bf(float lo, float hi) {
    unsigned a = __float_as_uint(lo) + 0x8000u;
    unsigned b = __float_as_uint(hi) + 0x8000u;
    return __builtin_amdgcn_perm(b, a, 0x07060302u);
}
// single-instruction 2^x (OCML exp2f without fast-math is ~12 VALU ops)
__device__ __forceinline__ float fast_exp2(float x) {
#if __has_builtin(__builtin_amdgcn_exp2f)
    return __builtin_amdgcn_exp2f(x);
#else
    float r;
    asm("v_exp_f32 %0, %1" : "=v"(r) : "v"(x));
    return r;
#endif
}
// async global->LDS DMA, 16B per lane; LDS dest = wave-uniform base + lane*16
__device__ __forceinline__ void gload16(const void* g, void* l) {
    __builtin_amdgcn_global_load_lds(
        (const __attribute__((address_space(1))) unsigned int*)g,
        (__attribute__((address_space(3))) unsigned int*)l, 16, 0, 0);
}

// device-scope grid barrier: monotone counter (never reset -> no ABA).
// Release-add publishes this block's writes (agent scope -> L2 writeback),
// acquire-load spin invalidates stale L1/L2 before consuming. All blocks are
// co-resident by construction, so the spin always terminates.
__device__ __forceinline__ void gbar(unsigned* cnt, unsigned target) {
    __threadfence();
    __syncthreads();
    if (threadIdx.x == 0) {
        __hip_atomic_fetch_add(cnt, 1u, __ATOMIC_RELEASE, __HIP_MEMORY_SCOPE_AGENT);
        while (__hip_atomic_load(cnt, __ATOMIC_ACQUIRE, __HIP_MEMORY_SCOPE_AGENT) < target)
            __builtin_amdgcn_s_sleep(8);
    }
    __syncthreads();
}

// ---------------------------------------------------------------------------
// Phase A body (r8 transpool_setup, re-indexed): b in [0,1024) transpose+pool;
// [1024,1344) weight cast; 1344 BN affine + bkv.
__device__ __forceinline__ void transpool_block(
    int b, char* smemc,
    const float* __restrict__ x, unsigned short* __restrict__ xbf,
    unsigned short* __restrict__ poolT,
    const float* __restrict__ w0, const float* __restrict__ w1,
    const float* __restrict__ w2, const float* __restrict__ w3,
    const float* __restrict__ w4, unsigned short* __restrict__ outW,
    const float* __restrict__ g1, const float* __restrict__ b1,
    const float* __restrict__ m1, const float* __restrict__ v1,
    const float* __restrict__ g2, const float* __restrict__ b2,
    const float* __restrict__ m2, const float* __restrict__ v2,
    float* __restrict__ scale, float* __restrict__ shift,
    const float* __restrict__ bk, const float* __restrict__ bv,
    float* __restrict__ bkv)
{
    float* T  = (float*)smemc;             // [64][65] = 16640 B
    float* P16 = (float*)(smemc + 16640);  // [64][17] = 4352 B (total 20992 < 32768)
    int t = threadIdx.x;
    if (b >= 1024) {
        int sb = b - 1024;
        if (sb < 320) {
            int gid = sb * 256 + t;
            int w = gid >> 14;
            int off = (gid & 16383) * 4;
            const float* src = (w == 0) ? w0 : (w == 1) ? w1 : (w == 2) ? w2 : (w == 3) ? w3 : w4;
            float4 v = *(const float4*)(src + off);
            uint2 pk;
            pk.x = pack2bf(v.x, v.y);
            pk.y = pack2bf(v.z, v.w);
            *(uint2*)(outW + w * 65536 + off) = pk;
        } else {
            float inv1 = g1[t] * rsqrtf(v1[t] + 1e-5f);
            float inv2 = g2[t] * rsqrtf(v2[t] + 1e-5f);
            scale[t] = inv1 * inv2;
            shift[t] = (b1[t] - m1[t] * inv1) * inv2 + (b2[t] - m2[t] * inv2);
            bkv[t] = bk[t];
            bkv[256 + t] = bv[t];
        }
        return;
    }
    int n = b >> 8, c0 = ((b >> 6) & 3) * 64, l0 = (b & 63) * 64;
    const float* xp = x + ((size_t)n * CH + c0) * LEN + l0;
    #pragma unroll
    for (int i = 0; i < 4; i++) {
        int idx = t + i * 256;
        int c = idx >> 4, l4 = idx & 15;
        float4 v = *(const float4*)(xp + (size_t)c * LEN + l4 * 4);
        T[c * 65 + l4 * 4 + 0] = v.x; T[c * 65 + l4 * 4 + 1] = v.y;
        T[c * 65 + l4 * 4 + 2] = v.z; T[c * 65 + l4 * 4 + 3] = v.w;
        P16[c * 17 + l4] = (v.x + v.y + v.z + v.w) * 0.25f
                         + fmaxf(fmaxf(v.x, v.y), fmaxf(v.z, v.w));
    }
    __syncthreads();
    unsigned short* op = xbf + ((size_t)n * LEN + l0) * CH + c0;
    #pragma unroll
    for (int i = 0; i < 4; i++) {
        int idx = t + i * 256;
        int l = idx >> 4, c4 = idx & 15;
        uint2 pk;
        pk.x = pack2bf(T[(c4 * 4 + 0) * 65 + l], T[(c4 * 4 + 1) * 65 + l]);
        pk.y = pack2bf(T[(c4 * 4 + 2) * 65 + l], T[(c4 * 4 + 3) * 65 + l]);
        *(uint2*)(op + (size_t)l * CH + c4 * 4) = pk;
    }
    int p0 = l0 >> 2;
    #pragma unroll
    for (int k = 0; k < 2; k++) {
        int p = (t >> 5) + k * 8;
        int c2 = (t & 31) * 2;
        unsigned pk = pack2bf(P16[c2 * 17 + p], P16[(c2 + 1) * 17 + p]);
        *(unsigned*)(poolT + ((size_t)n * LPOOL + p0 + p) * CH + c0 + c2) = pk;
    }
}

// ---------------------------------------------------------------------------
// GEMM block body (r8-proven async-DMA schedule, BM=64 x BN=64, BK=64, K=256):
// per K-step: vmcnt(0) ; s_barrier ; issue DMA(s+1) ; compute(s).
// smem carve: AsB[2] @ 0/8192, BsB[2] @ 16384/24576 (one array -> epilogue
// f32 restage spanning both B buffers is well-defined).
__device__ __forceinline__ void gemm_block(
    int bx, int by, int bz, char* smemc,
    const unsigned short* __restrict__ A,
    const unsigned short* __restrict__ B, size_t bBatch,
    const float* __restrict__ biasRow,
    const float* __restrict__ scale, const float* __restrict__ shift,
    float* __restrict__ outF, size_t oFBatch,
    unsigned short* __restrict__ out1, size_t o1Batch, int cs1,
    unsigned short* __restrict__ out2, size_t o2Batch, int rs2, int rowSplit,
    int NN, float outScale)
{
    char* AsB[2] = { smemc,         smemc + 8192 };
    char* BsB[2] = { smemc + 16384, smemc + 24576 };

    int n = bz;
    int t = threadIdx.x;
    int wave = t >> 6, lane = t & 63, m = lane & 15, quad = lane >> 4;
    int wm = wave & 1, wn = wave >> 1;
    int rowTile = by * 64;
    int col0 = bx * 64;

    const unsigned short* Ab = A + (size_t)rowTile * 256;
    const unsigned short* Bb = B + (size_t)n * bBatch + (size_t)col0 * 256;

    float4e acc[2][2] = {};

    int srow[2], sch[2], ldsW[2];
    #pragma unroll
    for (int i = 0; i < 2; i++) {
        int idx = t + i * 256;
        srow[i] = idx >> 3;
        sch[i]  = idx & 7;
        ldsW[i] = wave * 1024 + i * 4096;
    }
    int aoff[2][2], boff[2][2];
    #pragma unroll
    for (int i = 0; i < 2; i++) {
        int ra = wm * 32 + i * 16 + m;
        int rb = wn * 32 + i * 16 + m;
        #pragma unroll
        for (int kc = 0; kc < 2; kc++) {
            aoff[i][kc] = ra * 128 + kc * 64 + quad * 16;
            boff[i][kc] = rb * 128 + kc * 64 + quad * 16;
        }
    }

    // prologue: DMA K-step 0 -> buf 0
    #pragma unroll
    for (int i = 0; i < 2; i++) {
        gload16(Ab + (size_t)srow[i] * 256 + sch[i] * 8, AsB[0] + ldsW[i]);
        gload16(Bb + (size_t)srow[i] * 256 + sch[i] * 8, BsB[0] + ldsW[i]);
    }

    #pragma unroll
    for (int s = 0; s < 4; s++) {
        int cur = s & 1;
        asm volatile("s_waitcnt vmcnt(0)" ::: "memory");
        __builtin_amdgcn_sched_barrier(0);
        __builtin_amdgcn_s_barrier();
        __builtin_amdgcn_sched_barrier(0);
        if (s < 3) {
            int nxt = cur ^ 1;
            int kk = (s + 1) * 64;
            #pragma unroll
            for (int i = 0; i < 2; i++) {
                gload16(Ab + (size_t)srow[i] * 256 + kk + sch[i] * 8, AsB[nxt] + ldsW[i]);
                gload16(Bb + (size_t)srow[i] * 256 + kk + sch[i] * 8, BsB[nxt] + ldsW[i]);
            }
        }
        const char* AsC = AsB[cur];
        const char* BsC = BsB[cur];
        #pragma unroll
        for (int kc = 0; kc < 2; kc++) {
            short8 af[2], bfr[2];
            #pragma unroll
            for (int i = 0; i < 2; i++) {
                af[i]  = *(const short8*)(AsC + aoff[i][kc]);
                bfr[i] = *(const short8*)(BsC + boff[i][kc]);
            }
            __builtin_amdgcn_s_setprio(1);
            #pragma unroll
            for (int i = 0; i < 2; i++)
                #pragma unroll
                for (int j = 0; j < 2; j++)
                    acc[i][j] = __builtin_amdgcn_mfma_f32_16x16x32_bf16(af[i], bfr[j], acc[i][j], 0, 0, 0);
            __builtin_amdgcn_s_setprio(0);
        }
    }
    __syncthreads();   // all waves done reading LDS; safe to reuse B-bufs

    if (outF) {
        float* TOf = (float*)BsB[0];   // 64x64 f32 = 16 KB = both B buffers
        float* dst = outF + (size_t)n * oFBatch;
        #pragma unroll
        for (int i = 0; i < 2; i++) {
            int rowL = wm * 32 + i * 16 + quad * 4;
            int rowG = rowTile + rowL;
            float br[4], sc[4], sh[4];
            #pragma unroll
            for (int r = 0; r < 4; r++) {
                br[r] = biasRow ? biasRow[rowG + r] : 0.0f;
                sc[r] = scale ? scale[rowG + r] : 1.0f;
                sh[r] = shift ? shift[rowG + r] : 0.0f;
            }
            #pragma unroll
            for (int j = 0; j < 2; j++) {
                int colL = wn * 32 + j * 16 + m;
                float4e c = acc[i][j];
                #pragma unroll
                for (int r = 0; r < 4; r++)
                    TOf[(rowL + r) * 64 + colL] = ((c[r] + br[r]) * sc[r] + sh[r]) * outScale;
            }
        }
        __syncthreads();
        #pragma unroll
        for (int w = 0; w < 4; w++) {
            int idx = t + w * 256;
            int row = idx >> 4, c4 = idx & 15;
            *(float4*)(dst + (size_t)(rowTile + row) * NN + col0 + c4 * 4) =
                *(const float4*)&TOf[row * 64 + c4 * 4];
        }
        return;
    }

    bool mode2 = (rowTile >= rowSplit);
    unsigned short* TO = (unsigned short*)BsB[0];   // <= 9.2 KB used
    #pragma unroll
    for (int i = 0; i < 2; i++) {
        int rowL = wm * 32 + i * 16 + quad * 4;
        int rowG = rowTile + rowL;
        float br[4], sc[4], sh[4];
        #pragma unroll
        for (int r = 0; r < 4; r++) {
            br[r] = biasRow ? biasRow[rowG + r] : 0.0f;
            sc[r] = scale ? scale[rowG + r] : 1.0f;
            sh[r] = shift ? shift[rowG + r] : 0.0f;
        }
        #pragma unroll
        for (int j = 0; j < 2; j++) {
            int colL = wn * 32 + j * 16 + m;
            float4e c = acc[i][j];
            float v0 = ((c[0] + br[0]) * sc[0] + sh[0]) * outScale;
            float v1 = ((c[1] + br[1]) * sc[1] + sh[1]) * outScale;
            float v2 = ((c[2] + br[2]) * sc[2] + sh[2]) * outScale;
            float v3 = ((c[3] + br[3]) * sc[3] + sh[3]) * outScale;
            if (!mode2) {
                uint2 pk;
                pk.x = pack2bf(v0, v1);
                pk.y = pack2bf(v2, v3);
                *(uint2*)&TO[colL * 72 + rowL] = pk;
            } else {
                TO[(rowL + 0) * 72 + colL] = f2bf(v0);
                TO[(rowL + 1) * 72 + colL] = f2bf(v1);
                TO[(rowL + 2) * 72 + colL] = f2bf(v2);
                TO[(rowL + 3) * 72 + colL] = f2bf(v3);
            }
        }
    }
    __syncthreads();
    if (!mode2) {
        unsigned short* dst = out1 + (size_t)n * o1Batch;
        #pragma unroll
        for (int w = 0; w < 2; w++) {
            int idx = t + w * 256;
            int l = idx >> 3, ch = idx & 7;
            *(uint4*)(dst + (size_t)(col0 + l) * cs1 + rowTile + ch * 8) =
                *(const uint4*)&TO[l * 72 + ch * 8];
        }
    } else {
        unsigned short* dst = out2 + (size_t)n * o2Batch;
        int rowBase = rowTile - rowSplit;
        #pragma unroll
        for (int w = 0; w < 2; w++) {
            int idx = t + w * 256;
            int row = idx >> 3, ch = idx & 7;
            *(uint4*)(dst + (size_t)(rowBase + row) * rs2 + col0 + ch * 8) =
                *(const uint4*)&TO[row * 72 + ch * 8];
        }
    }
}

// ---------------------------------------------------------------------------
// Attention block body — r5/r7/r8-proven async-DMA version, logic unchanged.
__device__ __forceinline__ void attn_block(
    int qb, int h, int n, char* smemc,
    const unsigned short* __restrict__ Qb,
    const unsigned short* __restrict__ Kb,
    const unsigned short* __restrict__ Vb,
    unsigned short* __restrict__ Obf)
{
    char* KsB[2] = { smemc,         smemc + 8192 };
    char* VsB[2] = { smemc + 16384, smemc + 24576 };

    int t  = threadIdx.x;
    int wave = t >> 6, lane = t & 63;
    int col = lane & 31;
    int hi  = lane >> 5;
    int l0 = qb * 128 + wave * 32;

    const unsigned short* qp = Qb + ((size_t)n * LEN + l0 + col) * CH + h * HD + hi * 8;
    short8 bQ[4];
    #pragma unroll
    for (int dc = 0; dc < 4; dc++)
        bQ[dc] = *(const short8*)(qp + dc * 16);

    float16e Oa[2];
    #pragma unroll
    for (int e = 0; e < 2; e++)
        #pragma unroll
        for (int r = 0; r < 16; r++) Oa[e][r] = 0.0f;
    float l_run = 0.0f;

    const unsigned short* KgBase = Kb + (size_t)n * LPOOL * CH + h * HD;
    const unsigned short* VgBase = Vb + ((size_t)n * CH + h * HD) * LPOOL;
    const float NEG = -17.312340f;   // -12 * log2(e)

    int srow[2], schs[2], ldsb[2];
    #pragma unroll
    for (int i = 0; i < 2; i++) {
        int idx = t + i * 256;
        srow[i] = idx >> 3;
        schs[i] = (idx & 7) ^ (srow[i] & 7);
        ldsb[i] = wave * 1024 + i * 4096;
    }
    int ldoff[2][4];
    #pragma unroll
    for (int g = 0; g < 2; g++)
        #pragma unroll
        for (int c = 0; c < 4; c++) {
            int row = g * 32 + col;
            ldoff[g][c] = row * 128 + ((c * 32 + hi * 16) ^ ((row & 7) << 4));
        }

    #pragma unroll
    for (int i = 0; i < 2; i++) {
        gload16(KgBase + (size_t)srow[i] * CH + schs[i] * 8, KsB[0] + ldsb[i]);
        gload16(VgBase + (size_t)srow[i] * LPOOL + schs[i] * 8, VsB[0] + ldsb[i]);
    }

    #pragma unroll 2
    for (int kt = 0; kt < 16; kt++) {
        int cur = kt & 1;
        asm volatile("s_waitcnt vmcnt(0)" ::: "memory");
        __builtin_amdgcn_sched_barrier(0);
        __builtin_amdgcn_s_barrier();
        __builtin_amdgcn_sched_barrier(0);
        if (kt < 15) {
            int nxt = cur ^ 1;
            const unsigned short* ksrc = KgBase + (size_t)(kt + 1) * 64 * CH;
            const unsigned short* vsrc = VgBase + (kt + 1) * 64;
            #pragma unroll
            for (int i = 0; i < 2; i++) {
                gload16(ksrc + (size_t)srow[i] * CH + schs[i] * 8, KsB[nxt] + ldsb[i]);
                gload16(vsrc + (size_t)srow[i] * LPOOL + schs[i] * 8, VsB[nxt] + ldsb[i]);
            }
        }

        const char* KsC = KsB[cur];
        const char* VsC = VsB[cur];
        #pragma unroll
        for (int kh = 0; kh < 2; kh++) {
            float16e c;
            #pragma unroll
            for (int r = 0; r < 16; r++) c[r] = NEG;
            __builtin_amdgcn_s_setprio(1);
            #pragma unroll
            for (int dc = 0; dc < 4; dc++) {
                short8 a = *(const short8*)(KsC + ldoff[kh][dc]);
                c = __builtin_amdgcn_mfma_f32_32x32x16_bf16(a, bQ[dc], c, 0, 0, 0);
            }
            __builtin_amdgcn_s_setprio(0);
            float p[16];
            #pragma unroll
            for (int r = 0; r < 16; r++) p[r] = fast_exp2(c[r]);
            l_run += ((p[0] + p[1]) + (p[2] + p[3])) + ((p[4] + p[5]) + (p[6] + p[7]))
                   + ((p[8] + p[9]) + (p[10] + p[11])) + ((p[12] + p[13]) + (p[14] + p[15]));
            union { unsigned u[4]; short8 s; } bP[2];
            #pragma unroll
            for (int kc2 = 0; kc2 < 2; kc2++) {
                int rb = kc2 * 8;
                unsigned A0 = pack2bf(p[rb + 0], p[rb + 1]);
                unsigned B0 = pack2bf(p[rb + 4], p[rb + 5]);
                unsigned A1 = pack2bf(p[rb + 2], p[rb + 3]);
                unsigned B1 = pack2bf(p[rb + 6], p[rb + 7]);
                uint2v s0 = __builtin_amdgcn_permlane32_swap(A0, B0, false, false);
                uint2v s1 = __builtin_amdgcn_permlane32_swap(A1, B1, false, false);
                bP[kc2].u[0] = s0[0];
                bP[kc2].u[1] = s1[0];
                bP[kc2].u[2] = s0[1];
                bP[kc2].u[3] = s1[1];
            }
            __builtin_amdgcn_s_setprio(1);
            #pragma unroll
            for (int eh = 0; eh < 2; eh++)
                #pragma unroll
                for (int kc2 = 0; kc2 < 2; kc2++) {
                    short8 av = *(const short8*)(VsC + ldoff[eh][kh * 2 + kc2]);
                    Oa[eh] = __builtin_amdgcn_mfma_f32_32x32x16_bf16(av, bP[kc2].s, Oa[eh], 0, 0, 0);
                }
            __builtin_amdgcn_s_setprio(0);
        }
    }

    float l = l_run + __shfl_xor(l_run, 32);
    float inv = 1.0f / l;
    unsigned short* op = Obf + ((size_t)n * LEN + l0 + col) * CH + h * HD + hi * 4;
    #pragma unroll
    for (int eh = 0; eh < 2; eh++)
        #pragma unroll
        for (int rq = 0; rq < 4; rq++) {
            int r = rq * 4;
            uint2 pk;
            pk.x = pack2bf(Oa[eh][r + 0] * inv, Oa[eh][r + 1] * inv);
            pk.y = pack2bf(Oa[eh][r + 2] * inv, Oa[eh][r + 3] * inv);
            *(uint2*)(op + eh * 32 + rq * 8) = pk;
        }
}

// ---------------------------------------------------------------------------
// Mega-kernel: the whole pipeline in one dispatch, phases separated by
// device-scope grid barriers. 512 blocks x 256 threads, 32 KB LDS.
__global__ __launch_bounds__(256, 2) void mega(
    const float* __restrict__ x,
    const float* __restrict__ Wq, const float* __restrict__ bq,
    const float* __restrict__ Wk, const float* __restrict__ bk,
    const float* __restrict__ Wv, const float* __restrict__ bv,
    const float* __restrict__ Wo, const float* __restrict__ bo,
    const float* __restrict__ Wa,
    const float* __restrict__ g1, const float* __restrict__ b1,
    const float* __restrict__ m1, const float* __restrict__ v1,
    const float* __restrict__ g2, const float* __restrict__ b2,
    const float* __restrict__ m2, const float* __restrict__ v2,
    float* __restrict__ bn_scale, float* __restrict__ bn_shift,
    float* __restrict__ bkv,
    unsigned short* __restrict__ Wbf, unsigned short* __restrict__ xbf,
    unsigned short* __restrict__ poolT, unsigned short* __restrict__ xabf,
    unsigned short* __restrict__ Kbf, unsigned short* __restrict__ Vbf,
    unsigned short* __restrict__ Qbf, unsigned short* __restrict__ Obf,
    float* __restrict__ outp, unsigned* __restrict__ gcnt)
{
    __shared__ __align__(16) char smem[32768];
    int bid = blockIdx.x;

    // Phase A: transpose+pool + weight cast + BN affine (1345 works)
    for (int b = bid; b < 1345; b += NBLK) {
        __syncthreads();
        transpool_block(b, smem, x, xbf, poolT, Wq, Wk, Wv, Wo, Wa, Wbf,
                        g1, b1, m1, v1, g2, b2, m2, v2,
                        bn_scale, bn_shift, bk, bv, bkv);
    }
    gbar(gcnt, NBLK);

    // Phase B: q-proj (1024 works) + xa = BN(Wa @ pool) (256 works) — independent
    for (int vb = bid; vb < 1280; vb += NBLK) {
        __syncthreads();
        if (vb < 1024) {
            int bx = vb & 63, by = (vb >> 6) & 3, bz = vb >> 8;
            gemm_block(bx, by, bz, smem, Wbf + 0 * 65536, xbf, (size_t)LEN * CH,
                       bq, nullptr, nullptr, nullptr, 0,
                       Qbf, (size_t)LEN * CH, 256, nullptr, 0, 0, 1 << 30,
                       LEN, 0.18033688f);
        } else {
            int v2b = vb - 1024;
            int bx = v2b & 15, by = (v2b >> 4) & 3, bz = v2b >> 6;
            gemm_block(bx, by, bz, smem, Wbf + 4 * 65536, poolT, (size_t)LPOOL * CH,
                       nullptr, bn_scale, bn_shift, nullptr, 0,
                       xabf, (size_t)LPOOL * CH, 256, nullptr, 0, 0, 1 << 30,
                       LPOOL, 1.0f);
        }
    }
    gbar(gcnt, 2 * NBLK);

    // Phase C: fused k+v (512 works, exactly one per block)
    {
        int bx = bid & 15, by = (bid >> 4) & 7, bz = bid >> 7;
        gemm_block(bx, by, bz, smem, Wbf + 1 * 65536, xabf, (size_t)LPOOL * CH,
                   bkv, nullptr, nullptr, nullptr, 0,
                   Kbf, (size_t)LPOOL * CH, 256, Vbf, (size_t)LPOOL * CH, LPOOL, 256,
                   LPOOL, 1.0f);
    }
    gbar(gcnt, 3 * NBLK);

    // Phase D: attention (512 works, exactly one per block)
    {
        int qb = bid & 31, h = (bid >> 5) & 3, n = bid >> 7;
        attn_block(qb, h, n, smem, Qbf, Kbf, Vbf, Obf);
    }
    gbar(gcnt, 4 * NBLK);

    // Phase E: o-proj -> f32 output (1024 works)
    for (int vb = bid; vb < 1024; vb += NBLK) {
        __syncthreads();
        int bx = vb & 63, by = (vb >> 6) & 3, bz = vb >> 8;
        gemm_block(bx, by, bz, smem, Wbf + 3 * 65536, Obf, (size_t)LEN * CH,
                   bo, nullptr, nullptr, outp, (size_t)CH * LEN,
                   nullptr, 0, 0, nullptr, 0, 0, 1 << 30,
                   LEN, 1.0f);
    }
}

// ---------------------------------------------------------------------------
extern "C" void kernel_launch(void* const* d_in, const int* in_sizes, int n_in,
                              void* d_out, int out_size, void* d_ws, size_t ws_size,
                              hipStream_t stream)
{
    const float* x  = (const float*)d_in[0];
    const float* Wq = (const float*)d_in[1];
    const float* bq = (const float*)d_in[2];
    const float* Wk = (const float*)d_in[3];
    const float* bk = (const float*)d_in[4];
    const float* Wv = (const float*)d_in[5];
    const float* bv = (const float*)d_in[6];
    const float* Wo = (const float*)d_in[7];
    const float* bo = (const float*)d_in[8];
    const float* Wa = (const float*)d_in[9];
    const float* g1 = (const float*)d_in[10];
    const float* b1 = (const float*)d_in[11];
    const float* m1 = (const float*)d_in[12];
    const float* v1 = (const float*)d_in[13];
    const float* g2 = (const float*)d_in[14];
    const float* b2 = (const float*)d_in[15];
    const float* m2 = (const float*)d_in[16];
    const float* v2 = (const float*)d_in[17];

    float* wsf      = (float*)d_ws;
    float* bn_scale = wsf;            // 256
    float* bn_shift = wsf + 256;      // 256
    float* bkv      = wsf + 512;      // 512
    unsigned short* Wbf   = (unsigned short*)(wsf + 1024);          // 5*65536
    unsigned short* xbf   = Wbf + 5 * 65536;                        // [N,L,C]
    unsigned short* poolT = xbf   + (size_t)NBATCH * LEN * CH;      // [N,L2,C]
    unsigned short* xabf  = poolT + (size_t)NBATCH * LPOOL * CH;    // [N,L2,C]
    unsigned short* Kbf   = xabf  + (size_t)NBATCH * LPOOL * CH;    // [N,L2,C]
    unsigned short* Vbf   = Kbf   + (size_t)NBATCH * LPOOL * CH;    // [N,C,L2]
    unsigned short* Qbf   = Vbf   + (size_t)NBATCH * LPOOL * CH;    // [N,L,C]
    unsigned short* Obf   = Qbf   + (size_t)NBATCH * LEN * CH;      // [N,L,C]
    unsigned* gcnt = (unsigned*)(Obf + (size_t)NBATCH * LEN * CH);  // barrier counter

    hipMemsetAsync(gcnt, 0, sizeof(unsigned), stream);
    mega<<<NBLK, 256, 0, stream>>>(
        x, Wq, bq, Wk, bk, Wv, bv, Wo, bo, Wa,
        g1, b1, m1, v1, g2, b2, m2, v2,
        bn_scale, bn_shift, bkv,
        Wbf, xbf, poolT, xabf, Kbf, Vbf, Qbf, Obf,
        (float*)d_out, gcnt);
}

// Round 10
// 151.910 us; speedup vs baseline: 3.4514x; 3.4514x over previous
//
#include <hip/hip_runtime.h>
#include <stdint.h>

// Problem constants
constexpr int NBATCH = 4;
constexpr int CH     = 256;   // channels
constexpr int LEN    = 4096;  // sequence length
constexpr int LPOOL  = 1024;  // pooled length (LEN/4)
constexpr int NH     = 4;     // heads
constexpr int HD     = 64;    // head dim

typedef __attribute__((ext_vector_type(8))) short short8;     // 8 bf16 in 4 VGPRs
typedef __attribute__((ext_vector_type(4))) float float4e;    // MFMA C/D 16x16
typedef __attribute__((ext_vector_type(16))) float float16e;  // MFMA C/D 32x32
typedef __attribute__((ext_vector_type(2))) unsigned uint2v;

__device__ __forceinline__ unsigned short f2bf(float f) {
    union { unsigned int i; float f; } v; v.f = f;
    unsigned int lsb = (v.i >> 16) & 1u;
    v.i += 0x7fffu + lsb;
    return (unsigned short)(v.i >> 16);
}
// pack two floats -> two bf16 (round-half-up via +0x8000, then byte-perm)
__device__ __forceinline__ unsigned pack2bf(float lo, float hi) {
    unsigned a = __float_as_uint(lo) + 0x8000u;
    unsigned b = __float_as_uint(hi) + 0x8000u;
    return __builtin_amdgcn_perm(b, a, 0x07060302u);
}
// single-instruction 2^x (OCML exp2f without fast-math is ~12 VALU ops)
__device__ __forceinline__ float fast_exp2(float x) {
#if __has_builtin(__builtin_amdgcn_exp2f)
    return __builtin_amdgcn_exp2f(x);
#else
    float r;
    asm("v_exp_f32 %0, %1" : "=v"(r) : "v"(x));
    return r;
#endif
}
// async global->LDS DMA, 16B per lane; LDS dest = wave-uniform base + lane*16
__device__ __forceinline__ void gload16(const void* g, void* l) {
    __builtin_amdgcn_global_load_lds(
        (const __attribute__((address_space(1))) unsigned int*)g,
        (__attribute__((address_space(3))) unsigned int*)l, 16, 0, 0);
}

// ---------------------------------------------------------------------------
// Phase A body (correctness-proven in r9 mega): b in [0,1024) transpose+pool;
// [1024,1344) weight cast; 1344 BN affine + bkv.
__device__ __forceinline__ void transpool_block(
    int b, char* smemc,
    const float* __restrict__ x, unsigned short* __restrict__ xbf,
    unsigned short* __restrict__ poolT,
    const float* __restrict__ w0, const float* __restrict__ w1,
    const float* __restrict__ w2, const float* __restrict__ w3,
    const float* __restrict__ w4, unsigned short* __restrict__ outW,
    const float* __restrict__ g1, const float* __restrict__ b1,
    const float* __restrict__ m1, const float* __restrict__ v1,
    const float* __restrict__ g2, const float* __restrict__ b2,
    const float* __restrict__ m2, const float* __restrict__ v2,
    float* __restrict__ scale, float* __restrict__ shift,
    const float* __restrict__ bk, const float* __restrict__ bv,
    float* __restrict__ bkv)
{
    float* T   = (float*)smemc;            // [64][65] = 16640 B
    float* P16 = (float*)(smemc + 16640);  // [64][17] = 4352 B
    int t = threadIdx.x;
    if (b >= 1024) {
        int sb = b - 1024;
        if (sb < 320) {
            int gid = sb * 256 + t;
            int w = gid >> 14;
            int off = (gid & 16383) * 4;
            const float* src = (w == 0) ? w0 : (w == 1) ? w1 : (w == 2) ? w2 : (w == 3) ? w3 : w4;
            float4 v = *(const float4*)(src + off);
            uint2 pk;
            pk.x = pack2bf(v.x, v.y);
            pk.y = pack2bf(v.z, v.w);
            *(uint2*)(outW + w * 65536 + off) = pk;
        } else {
            float inv1 = g1[t] * rsqrtf(v1[t] + 1e-5f);
            float inv2 = g2[t] * rsqrtf(v2[t] + 1e-5f);
            scale[t] = inv1 * inv2;
            shift[t] = (b1[t] - m1[t] * inv1) * inv2 + (b2[t] - m2[t] * inv2);
            bkv[t] = bk[t];
            bkv[256 + t] = bv[t];
        }
        return;
    }
    int n = b >> 8, c0 = ((b >> 6) & 3) * 64, l0 = (b & 63) * 64;
    const float* xp = x + ((size_t)n * CH + c0) * LEN + l0;
    #pragma unroll
    for (int i = 0; i < 4; i++) {
        int idx = t + i * 256;
        int c = idx >> 4, l4 = idx & 15;
        float4 v = *(const float4*)(xp + (size_t)c * LEN + l4 * 4);
        T[c * 65 + l4 * 4 + 0] = v.x; T[c * 65 + l4 * 4 + 1] = v.y;
        T[c * 65 + l4 * 4 + 2] = v.z; T[c * 65 + l4 * 4 + 3] = v.w;
        P16[c * 17 + l4] = (v.x + v.y + v.z + v.w) * 0.25f
                         + fmaxf(fmaxf(v.x, v.y), fmaxf(v.z, v.w));
    }
    __syncthreads();
    unsigned short* op = xbf + ((size_t)n * LEN + l0) * CH + c0;
    #pragma unroll
    for (int i = 0; i < 4; i++) {
        int idx = t + i * 256;
        int l = idx >> 4, c4 = idx & 15;
        uint2 pk;
        pk.x = pack2bf(T[(c4 * 4 + 0) * 65 + l], T[(c4 * 4 + 1) * 65 + l]);
        pk.y = pack2bf(T[(c4 * 4 + 2) * 65 + l], T[(c4 * 4 + 3) * 65 + l]);
        *(uint2*)(op + (size_t)l * CH + c4 * 4) = pk;
    }
    int p0 = l0 >> 2;
    #pragma unroll
    for (int k = 0; k < 2; k++) {
        int p = (t >> 5) + k * 8;
        int c2 = (t & 31) * 2;
        unsigned pk = pack2bf(P16[c2 * 17 + p], P16[(c2 + 1) * 17 + p]);
        *(unsigned*)(poolT + ((size_t)n * LPOOL + p0 + p) * CH + c0 + c2) = pk;
    }
}

__global__ __launch_bounds__(256) void transpool_setup(
    const float* __restrict__ x, unsigned short* __restrict__ xbf,
    unsigned short* __restrict__ poolT,
    const float* __restrict__ w0, const float* __restrict__ w1,
    const float* __restrict__ w2, const float* __restrict__ w3,
    const float* __restrict__ w4, unsigned short* __restrict__ outW,
    const float* __restrict__ g1, const float* __restrict__ b1,
    const float* __restrict__ m1, const float* __restrict__ v1,
    const float* __restrict__ g2, const float* __restrict__ b2,
    const float* __restrict__ m2, const float* __restrict__ v2,
    float* __restrict__ scale, float* __restrict__ shift,
    const float* __restrict__ bk, const float* __restrict__ bv,
    float* __restrict__ bkv)
{
    __shared__ __align__(16) char smem[20992];
    transpool_block(blockIdx.x, smem, x, xbf, poolT, w0, w1, w2, w3, w4, outW,
                    g1, b1, m1, v1, g2, b2, m2, v2, scale, shift, bk, bv, bkv);
}

// ---------------------------------------------------------------------------
// GEMM block body (r8 schedule, correctness-proven in r9 mega): BM=64 x BN=64,
// BK=64, K=256, async-DMA double-buffered, per K-step:
// vmcnt(0) ; s_barrier ; issue DMA(s+1) ; compute(s).
// smem carve: AsB[2] @ 0/8192, BsB[2] @ 16384/24576 (single allocation ->
// epilogue f32 restage spanning both B buffers is well-defined).
__device__ __forceinline__ void gemm_block(
    int bx, int by, int bz, char* smemc,
    const unsigned short* __restrict__ A,
    const unsigned short* __restrict__ B, size_t bBatch,
    const float* __restrict__ biasRow,
    const float* __restrict__ scale, const float* __restrict__ shift,
    float* __restrict__ outF, size_t oFBatch,
    unsigned short* __restrict__ out1, size_t o1Batch, int cs1,
    unsigned short* __restrict__ out2, size_t o2Batch, int rs2, int rowSplit,
    int NN, float outScale)
{
    char* AsB[2] = { smemc,         smemc + 8192 };
    char* BsB[2] = { smemc + 16384, smemc + 24576 };

    int n = bz;
    int t = threadIdx.x;
    int wave = t >> 6, lane = t & 63, m = lane & 15, quad = lane >> 4;
    int wm = wave & 1, wn = wave >> 1;
    int rowTile = by * 64;
    int col0 = bx * 64;

    const unsigned short* Ab = A + (size_t)rowTile * 256;
    const unsigned short* Bb = B + (size_t)n * bBatch + (size_t)col0 * 256;

    float4e acc[2][2] = {};

    int srow[2], sch[2], ldsW[2];
    #pragma unroll
    for (int i = 0; i < 2; i++) {
        int idx = t + i * 256;
        srow[i] = idx >> 3;
        sch[i]  = idx & 7;
        ldsW[i] = wave * 1024 + i * 4096;
    }
    int aoff[2][2], boff[2][2];
    #pragma unroll
    for (int i = 0; i < 2; i++) {
        int ra = wm * 32 + i * 16 + m;
        int rb = wn * 32 + i * 16 + m;
        #pragma unroll
        for (int kc = 0; kc < 2; kc++) {
            aoff[i][kc] = ra * 128 + kc * 64 + quad * 16;
            boff[i][kc] = rb * 128 + kc * 64 + quad * 16;
        }
    }

    #pragma unroll
    for (int i = 0; i < 2; i++) {
        gload16(Ab + (size_t)srow[i] * 256 + sch[i] * 8, AsB[0] + ldsW[i]);
        gload16(Bb + (size_t)srow[i] * 256 + sch[i] * 8, BsB[0] + ldsW[i]);
    }

    #pragma unroll
    for (int s = 0; s < 4; s++) {
        int cur = s & 1;
        asm volatile("s_waitcnt vmcnt(0)" ::: "memory");
        __builtin_amdgcn_sched_barrier(0);
        __builtin_amdgcn_s_barrier();
        __builtin_amdgcn_sched_barrier(0);
        if (s < 3) {
            int nxt = cur ^ 1;
            int kk = (s + 1) * 64;
            #pragma unroll
            for (int i = 0; i < 2; i++) {
                gload16(Ab + (size_t)srow[i] * 256 + kk + sch[i] * 8, AsB[nxt] + ldsW[i]);
                gload16(Bb + (size_t)srow[i] * 256 + kk + sch[i] * 8, BsB[nxt] + ldsW[i]);
            }
        }
        const char* AsC = AsB[cur];
        const char* BsC = BsB[cur];
        #pragma unroll
        for (int kc = 0; kc < 2; kc++) {
            short8 af[2], bfr[2];
            #pragma unroll
            for (int i = 0; i < 2; i++) {
                af[i]  = *(const short8*)(AsC + aoff[i][kc]);
                bfr[i] = *(const short8*)(BsC + boff[i][kc]);
            }
            __builtin_amdgcn_s_setprio(1);
            #pragma unroll
            for (int i = 0; i < 2; i++)
                #pragma unroll
                for (int j = 0; j < 2; j++)
                    acc[i][j] = __builtin_amdgcn_mfma_f32_16x16x32_bf16(af[i], bfr[j], acc[i][j], 0, 0, 0);
            __builtin_amdgcn_s_setprio(0);
        }
    }
    __syncthreads();

    if (outF) {
        float* TOf = (float*)BsB[0];   // 64x64 f32 = 16 KB = both B buffers
        float* dst = outF + (size_t)n * oFBatch;
        #pragma unroll
        for (int i = 0; i < 2; i++) {
            int rowL = wm * 32 + i * 16 + quad * 4;
            int rowG = rowTile + rowL;
            float br[4], sc[4], sh[4];
            #pragma unroll
            for (int r = 0; r < 4; r++) {
                br[r] = biasRow ? biasRow[rowG + r] : 0.0f;
                sc[r] = scale ? scale[rowG + r] : 1.0f;
                sh[r] = shift ? shift[rowG + r] : 0.0f;
            }
            #pragma unroll
            for (int j = 0; j < 2; j++) {
                int colL = wn * 32 + j * 16 + m;
                float4e c = acc[i][j];
                #pragma unroll
                for (int r = 0; r < 4; r++)
                    TOf[(rowL + r) * 64 + colL] = ((c[r] + br[r]) * sc[r] + sh[r]) * outScale;
            }
        }
        __syncthreads();
        #pragma unroll
        for (int w = 0; w < 4; w++) {
            int idx = t + w * 256;
            int row = idx >> 4, c4 = idx & 15;
            *(float4*)(dst + (size_t)(rowTile + row) * NN + col0 + c4 * 4) =
                *(const float4*)&TOf[row * 64 + c4 * 4];
        }
        return;
    }

    bool mode2 = (rowTile >= rowSplit);
    unsigned short* TO = (unsigned short*)BsB[0];
    #pragma unroll
    for (int i = 0; i < 2; i++) {
        int rowL = wm * 32 + i * 16 + quad * 4;
        int rowG = rowTile + rowL;
        float br[4], sc[4], sh[4];
        #pragma unroll
        for (int r = 0; r < 4; r++) {
            br[r] = biasRow ? biasRow[rowG + r] : 0.0f;
            sc[r] = scale ? scale[rowG + r] : 1.0f;
            sh[r] = shift ? shift[rowG + r] : 0.0f;
        }
        #pragma unroll
        for (int j = 0; j < 2; j++) {
            int colL = wn * 32 + j * 16 + m;
            float4e c = acc[i][j];
            float v0 = ((c[0] + br[0]) * sc[0] + sh[0]) * outScale;
            float v1 = ((c[1] + br[1]) * sc[1] + sh[1]) * outScale;
            float v2 = ((c[2] + br[2]) * sc[2] + sh[2]) * outScale;
            float v3 = ((c[3] + br[3]) * sc[3] + sh[3]) * outScale;
            if (!mode2) {
                uint2 pk;
                pk.x = pack2bf(v0, v1);
                pk.y = pack2bf(v2, v3);
                *(uint2*)&TO[colL * 72 + rowL] = pk;
            } else {
                TO[(rowL + 0) * 72 + colL] = f2bf(v0);
                TO[(rowL + 1) * 72 + colL] = f2bf(v1);
                TO[(rowL + 2) * 72 + colL] = f2bf(v2);
                TO[(rowL + 3) * 72 + colL] = f2bf(v3);
            }
        }
    }
    __syncthreads();
    if (!mode2) {
        unsigned short* dst = out1 + (size_t)n * o1Batch;
        #pragma unroll
        for (int w = 0; w < 2; w++) {
            int idx = t + w * 256;
            int l = idx >> 3, ch = idx & 7;
            *(uint4*)(dst + (size_t)(col0 + l) * cs1 + rowTile + ch * 8) =
                *(const uint4*)&TO[l * 72 + ch * 8];
        }
    } else {
        unsigned short* dst = out2 + (size_t)n * o2Batch;
        int rowBase = rowTile - rowSplit;
        #pragma unroll
        for (int w = 0; w < 2; w++) {
            int idx = t + w * 256;
            int row = idx >> 3, ch = idx & 7;
            *(uint4*)(dst + (size_t)(rowBase + row) * rs2 + col0 + ch * 8) =
                *(const uint4*)&TO[row * 72 + ch * 8];
        }
    }
}

// generic single-job GEMM wrapper (kv, o-proj)
__global__ __launch_bounds__(256, 4) void gemm_single(
    const unsigned short* __restrict__ A,
    const unsigned short* __restrict__ B, size_t bBatch,
    const float* __restrict__ biasRow,
    const float* __restrict__ scale, const float* __restrict__ shift,
    float* __restrict__ outF, size_t oFBatch,
    unsigned short* __restrict__ out1, size_t o1Batch, int cs1,
    unsigned short* __restrict__ out2, size_t o2Batch, int rs2, int rowSplit,
    int NN, float outScale)
{
    __shared__ __align__(16) char smem[32768];
    gemm_block(blockIdx.x, blockIdx.y, blockIdx.z, smem, A, B, bBatch,
               biasRow, scale, shift, outF, oFBatch,
               out1, o1Batch, cs1, out2, o2Batch, rs2, rowSplit, NN, outScale);
}

// merged q-proj + xa kernel: the two GEMMs are independent (both consume
// phase-A outputs), so one dispatch covers both. bx<64 -> q-proj tile bx;
// bx>=64 -> xa tile bx-64. Saves one launch + inter-dispatch drain.
__global__ __launch_bounds__(256, 4) void gemm_qxa(
    const unsigned short* __restrict__ Wqbf, const unsigned short* __restrict__ xbf,
    const float* __restrict__ bq, unsigned short* __restrict__ Qbf,
    const unsigned short* __restrict__ Wabf, const unsigned short* __restrict__ poolT,
    const float* __restrict__ bn_scale, const float* __restrict__ bn_shift,
    unsigned short* __restrict__ xabf)
{
    __shared__ __align__(16) char smem[32768];
    int bx = blockIdx.x;
    if (bx < 64) {
        gemm_block(bx, blockIdx.y, blockIdx.z, smem, Wqbf, xbf, (size_t)LEN * CH,
                   bq, nullptr, nullptr, nullptr, 0,
                   Qbf, (size_t)LEN * CH, 256, nullptr, 0, 0, 1 << 30,
                   LEN, 0.18033688f);
    } else {
        gemm_block(bx - 64, blockIdx.y, blockIdx.z, smem, Wabf, poolT, (size_t)LPOOL * CH,
                   nullptr, bn_scale, bn_shift, nullptr, 0,
                   xabf, (size_t)LPOOL * CH, 256, nullptr, 0, 0, 1 << 30,
                   LPOOL, 1.0f);
    }
}

// ---------------------------------------------------------------------------
// MFMA flash attention, 32x32x16, TRIPLE-buffered counted-vmcnt (T4 proper).
// vs r8 (vmcnt(0) per tile): tile kt's DMA had only tile kt-1's compute
// (~850 cyc) to cover ~500-900 cyc latency -> partial exposure every tile.
// Now 2 tiles in flight: per thread each tile = 4 loads (2K+2V, one issue
// group); at top of iter kt outstanding <= {kt, kt+1} = 8 loads; wait
// vmcnt(4) -> in-order completion (m135) guarantees tile kt landed while
// kt+1's 4 stay in flight. Tile kt+2 issued after the barrier into
// buf[(kt+2)%3] (distinct from the two live buffers; its prior readers
// finished before this barrier). Tail iter uses vmcnt(0). LDS 48 KB.
// Compute body unchanged from the r5/r7/r8-proven version.
__global__ __launch_bounds__(256, 2) void attn_mfma(
    const unsigned short* __restrict__ Qb,
    const unsigned short* __restrict__ Kb,
    const unsigned short* __restrict__ Vb,
    unsigned short* __restrict__ Obf)
{
    __shared__ unsigned short Ks[3][64 * 64];   // [key][dim], swizzled content
    __shared__ unsigned short Vs[3][64 * 64];   // [e][key],  swizzled content

    int qb = blockIdx.x;          // 128-row q block
    int h  = blockIdx.y;
    int n  = blockIdx.z;
    int t  = threadIdx.x;
    int wave = t >> 6, lane = t & 63;
    int col = lane & 31;          // q within wave
    int hi  = lane >> 5;
    int l0 = qb * 128 + wave * 32;

    const unsigned short* qp = Qb + ((size_t)n * LEN + l0 + col) * CH + h * HD + hi * 8;
    short8 bQ[4];
    #pragma unroll
    for (int dc = 0; dc < 4; dc++)
        bQ[dc] = *(const short8*)(qp + dc * 16);

    float16e Oa[2];
    #pragma unroll
    for (int e = 0; e < 2; e++)
        #pragma unroll
        for (int r = 0; r < 16; r++) Oa[e][r] = 0.0f;
    float l_run = 0.0f;

    const unsigned short* KgBase = Kb + (size_t)n * LPOOL * CH + h * HD;
    const unsigned short* VgBase = Vb + ((size_t)n * CH + h * HD) * LPOOL;
    const float NEG = -17.312340f;   // -12 * log2(e)

    int srow[2], schs[2], ldsb[2];
    #pragma unroll
    for (int i = 0; i < 2; i++) {
        int idx = t + i * 256;
        srow[i] = idx >> 3;
        schs[i] = (idx & 7) ^ (srow[i] & 7);
        ldsb[i] = wave * 1024 + i * 4096;   // wave-uniform DMA base (bytes)
    }
    int ldoff[2][4];
    #pragma unroll
    for (int g = 0; g < 2; g++)
        #pragma unroll
        for (int c = 0; c < 4; c++) {
            int row = g * 32 + col;
            ldoff[g][c] = row * 128 + ((c * 32 + hi * 16) ^ ((row & 7) << 4));
        }

    // one issue-group = 4 loads per thread per tile (2 K + 2 V)
    auto issue_tile = [&](int tile, int buf) {
        const unsigned short* ksrc = KgBase + (size_t)tile * 64 * CH;
        const unsigned short* vsrc = VgBase + tile * 64;
        #pragma unroll
        for (int i = 0; i < 2; i++)
            gload16(ksrc + (size_t)srow[i] * CH + schs[i] * 8, (char*)Ks[buf] + ldsb[i]);
        #pragma unroll
        for (int i = 0; i < 2; i++)
            gload16(vsrc + (size_t)srow[i] * LPOOL + schs[i] * 8, (char*)Vs[buf] + ldsb[i]);
    };

    auto tile_compute = [&](const char* KsC, const char* VsC) {
        #pragma unroll
        for (int kh = 0; kh < 2; kh++) {
            float16e c;
            #pragma unroll
            for (int r = 0; r < 16; r++) c[r] = NEG;
            __builtin_amdgcn_s_setprio(1);
            #pragma unroll
            for (int dc = 0; dc < 4; dc++) {
                short8 a = *(const short8*)(KsC + ldoff[kh][dc]);
                c = __builtin_amdgcn_mfma_f32_32x32x16_bf16(a, bQ[dc], c, 0, 0, 0);
            }
            __builtin_amdgcn_s_setprio(0);
            float p[16];
            #pragma unroll
            for (int r = 0; r < 16; r++) p[r] = fast_exp2(c[r]);
            l_run += ((p[0] + p[1]) + (p[2] + p[3])) + ((p[4] + p[5]) + (p[6] + p[7]))
                   + ((p[8] + p[9]) + (p[10] + p[11])) + ((p[12] + p[13]) + (p[14] + p[15]));
            union { unsigned u[4]; short8 s; } bP[2];
            #pragma unroll
            for (int kc2 = 0; kc2 < 2; kc2++) {
                int rb = kc2 * 8;
                unsigned A0 = pack2bf(p[rb + 0], p[rb + 1]);
                unsigned B0 = pack2bf(p[rb + 4], p[rb + 5]);
                unsigned A1 = pack2bf(p[rb + 2], p[rb + 3]);
                unsigned B1 = pack2bf(p[rb + 6], p[rb + 7]);
                uint2v s0 = __builtin_amdgcn_permlane32_swap(A0, B0, false, false);
                uint2v s1 = __builtin_amdgcn_permlane32_swap(A1, B1, false, false);
                bP[kc2].u[0] = s0[0];
                bP[kc2].u[1] = s1[0];
                bP[kc2].u[2] = s0[1];
                bP[kc2].u[3] = s1[1];
            }
            __builtin_amdgcn_s_setprio(1);
            #pragma unroll
            for (int eh = 0; eh < 2; eh++)
                #pragma unroll
                for (int kc2 = 0; kc2 < 2; kc2++) {
                    short8 av = *(const short8*)(VsC + ldoff[eh][kh * 2 + kc2]);
                    Oa[eh] = __builtin_amdgcn_mfma_f32_32x32x16_bf16(av, bP[kc2].s, Oa[eh], 0, 0, 0);
                }
            __builtin_amdgcn_s_setprio(0);
        }
    };

    // prologue: tiles 0,1 -> bufs 0,1 (two issue-groups, in order)
    issue_tile(0, 0);
    issue_tile(1, 1);

    int cur = 0;
    #pragma unroll 3
    for (int kt = 0; kt < 15; kt++) {
        // tile kt's 4 loads complete (kt+1's 4 may remain in flight)
        asm volatile("s_waitcnt vmcnt(4)" ::: "memory");
        __builtin_amdgcn_sched_barrier(0);
        __builtin_amdgcn_s_barrier();
        __builtin_amdgcn_sched_barrier(0);
        if (kt < 14) {
            int nb = cur - 1; if (nb < 0) nb = 2;   // (cur+2)%3
            issue_tile(kt + 2, nb);
        }
        tile_compute((const char*)Ks[cur], (const char*)Vs[cur]);
        cur = (cur == 2) ? 0 : cur + 1;
    }
    // tail: tile 15 (only its 4 loads can be outstanding)
    asm volatile("s_waitcnt vmcnt(0)" ::: "memory");
    __builtin_amdgcn_sched_barrier(0);
    __builtin_amdgcn_s_barrier();
    __builtin_amdgcn_sched_barrier(0);
    tile_compute((const char*)Ks[cur], (const char*)Vs[cur]);

    // normalize + store: e = (r&3) + 8*(r>>2) + 4*hi + 32*eh
    float l = l_run + __shfl_xor(l_run, 32);
    float inv = 1.0f / l;
    unsigned short* op = Obf + ((size_t)n * LEN + l0 + col) * CH + h * HD + hi * 4;
    #pragma unroll
    for (int eh = 0; eh < 2; eh++)
        #pragma unroll
        for (int rq = 0; rq < 4; rq++) {
            int r = rq * 4;
            uint2 pk;
            pk.x = pack2bf(Oa[eh][r + 0] * inv, Oa[eh][r + 1] * inv);
            pk.y = pack2bf(Oa[eh][r + 2] * inv, Oa[eh][r + 3] * inv);
            *(uint2*)(op + eh * 32 + rq * 8) = pk;
        }
}

// ---------------------------------------------------------------------------
extern "C" void kernel_launch(void* const* d_in, const int* in_sizes, int n_in,
                              void* d_out, int out_size, void* d_ws, size_t ws_size,
                              hipStream_t stream)
{
    const float* x  = (const float*)d_in[0];
    const float* Wq = (const float*)d_in[1];
    const float* bq = (const float*)d_in[2];
    const float* Wk = (const float*)d_in[3];
    const float* bk = (const float*)d_in[4];
    const float* Wv = (const float*)d_in[5];
    const float* bv = (const float*)d_in[6];
    const float* Wo = (const float*)d_in[7];
    const float* bo = (const float*)d_in[8];
    const float* Wa = (const float*)d_in[9];
    const float* g1 = (const float*)d_in[10];
    const float* b1 = (const float*)d_in[11];
    const float* m1 = (const float*)d_in[12];
    const float* v1 = (const float*)d_in[13];
    const float* g2 = (const float*)d_in[14];
    const float* b2 = (const float*)d_in[15];
    const float* m2 = (const float*)d_in[16];
    const float* v2 = (const float*)d_in[17];

    float* wsf      = (float*)d_ws;
    float* bn_scale = wsf;            // 256
    float* bn_shift = wsf + 256;      // 256
    float* bkv      = wsf + 512;      // 512
    unsigned short* Wbf   = (unsigned short*)(wsf + 1024);          // 5*65536
    unsigned short* xbf   = Wbf + 5 * 65536;                        // [N,L,C]
    unsigned short* poolT = xbf   + (size_t)NBATCH * LEN * CH;      // [N,L2,C]
    unsigned short* xabf  = poolT + (size_t)NBATCH * LPOOL * CH;    // [N,L2,C]
    unsigned short* Kbf   = xabf  + (size_t)NBATCH * LPOOL * CH;    // [N,L2,C]
    unsigned short* Vbf   = Kbf   + (size_t)NBATCH * LPOOL * CH;    // [N,C,L2]
    unsigned short* Qbf   = Vbf   + (size_t)NBATCH * LPOOL * CH;    // [N,L,C]
    unsigned short* Obf   = Qbf   + (size_t)NBATCH * LEN * CH;      // [N,L,C]

    // 1. transpose+pool over x, weights->bf16, BN affine, bkv concat
    transpool_setup<<<1345, 256, 0, stream>>>(x, xbf, poolT,
        Wq, Wk, Wv, Wo, Wa, Wbf,
        g1, b1, m1, v1, g2, b2, m2, v2, bn_scale, bn_shift, bk, bv, bkv);

    // 2. merged: q = Wq @ x + bq (bx<64) AND xa = BN(Wa @ pool) (bx>=64)
    gemm_qxa<<<dim3(80, 4, 4), 256, 0, stream>>>(
        Wbf + 0 * 65536, xbf, bq, Qbf,
        Wbf + 4 * 65536, poolT, bn_scale, bn_shift, xabf);

    // 3. fused k+v: A = [Wk;Wv], M=512. rows 0..255 -> Kbf [l2][c];
    //    rows 256..511 -> Vbf [c][l2]
    gemm_single<<<dim3(16, 8, 4), 256, 0, stream>>>(
        Wbf + 1 * 65536, xabf, (size_t)LPOOL * CH, bkv, nullptr, nullptr,
        nullptr, 0, Kbf, (size_t)LPOOL * CH, 256, Vbf, (size_t)LPOOL * CH, LPOOL, 256,
        LPOOL, 1.0f);

    // 4. attention -> Obf [N,L,C] bf16 (triple-buffered counted-vmcnt)
    attn_mfma<<<dim3(LEN / 128, NH, NBATCH), 256, 0, stream>>>(Qbf, Kbf, Vbf, Obf);

    // 5. out = Wo @ o + bo -> f32 d_out [N,C,L]
    gemm_single<<<dim3(64, 4, 4), 256, 0, stream>>>(
        Wbf + 3 * 65536, Obf, (size_t)LEN * CH, bo, nullptr, nullptr,
        (float*)d_out, (size_t)CH * LEN, nullptr, 0, 0, nullptr, 0, 0, 1 << 30,
        LEN, 1.0f);
}